// Round 1
// 67.132 us; speedup vs baseline: 1.0087x; 1.0087x over previous
//
#include <hip/hip_runtime.h>
#include <math.h>

// Problem constants (from reference setup_inputs)
#define BB 16
#define QQ 1000
#define CC 91
#define TT 128

#define COST_CLASS 2.0f
#define COST_BBOX  5.0f
#define COST_GIOU  2.0f
#define ALPHA 0.25f
#define GAMMA 2.0f
#define EPS   1e-8f

#define FOC_LD 92   // focal LDS row stride (91 classes + 1 pad)

// out[b,q,t] = COST_BBOX * L1(pbox[b,q], tbox[b,t])
//            + COST_CLASS * focal(sigmoid(logit[b,q,label[b,t]]))
//            + COST_GIOU * (-GIoU(xyxy(pbox), xyxy(tbox)))
//
// Block = 256 threads = 8 consecutive bq-rows x 32 t4-groups (8 | 1000, so a
// block never straddles a batch). Stage phase: compute cost_class once per
// (row, class) pair -- 8x91 = 728 transcendental chains per block instead of
// 8x128 = 1024, with fully-coalesced logits reads -- into LDS. Main loop then
// replaces {divergent global gather + exp/rcp/2xlog chain} per element with a
// single ds_read_b32. Math per element is bit-identical to the previous
// passing kernel (same hw rcp/exp/log), so absmax margin is unchanged.
__global__ __launch_bounds__(256) void matcher_kernel(
        const float* __restrict__ logits,   // [B,Q,C]
        const float* __restrict__ pboxes,   // [B,Q,4] cxcywh
        const int*   __restrict__ labels,   // [B,T]
        const float* __restrict__ tboxes,   // [B,T,4] cxcywh
        float* __restrict__ out)            // [B,Q,T]
{
    __shared__ float foc[8 * FOC_LD];       // 2944 B

    const int tid = threadIdx.x;
    const int bq0 = blockIdx.x * 8;         // first of 8 rows this block owns
    const int b   = bq0 / QQ;

    // ---- stage: focal cost_class for every (row, class) of this block ----
    const float* lbase = logits + (size_t)bq0 * CC;
    for (int k = tid; k < 8 * CC; k += 256) {
        const int row = k / CC;             // magic-mul div by 91
        const int col = k - row * CC;
        const float logit = lbase[k];       // coalesced: 2912 contiguous bytes
        const float p   = __builtin_amdgcn_rcpf(1.0f + __expf(-logit));
        const float omp = 1.0f - p;
        const float neg = (1.0f - ALPHA) * (p * p)     * (-__logf(omp + EPS));
        const float pos = ALPHA          * (omp * omp) * (-__logf(p + EPS));
        foc[row * FOC_LD + col] = pos - neg;
    }
    __syncthreads();

    // ---- main: 4 targets per thread, float4 I/O ----
    const int t4 = tid & 31;                // t-group: 4*t4 .. 4*t4+3
    const int r  = tid >> 5;                // row within block
    const int bq = bq0 + r;

    const float4 pb = *reinterpret_cast<const float4*>(pboxes + (size_t)bq * 4);
    const int4 lab4 = *reinterpret_cast<const int4*>(labels + b * TT + t4 * 4);

    const float ax0 = pb.x - 0.5f * pb.z, ay0 = pb.y - 0.5f * pb.w;
    const float ax1 = pb.x + 0.5f * pb.z, ay1 = pb.y + 0.5f * pb.w;
    const float area_a = (ax1 - ax0) * (ay1 - ay0);

    const float* trow = tboxes + ((size_t)b * TT + t4 * 4) * 4;
    const float* frow = foc + r * FOC_LD;

    float4 res;
    float* resp = &res.x;
    const int labs[4] = {lab4.x, lab4.y, lab4.z, lab4.w};

#pragma unroll
    for (int j = 0; j < 4; ++j) {
        const float4 tb = *reinterpret_cast<const float4*>(trow + j * 4);

        // ---- cost_class: single LDS gather (deduped focal) ----
        const float cost_class = frow[labs[j]];

        // ---- cost_bbox: L1 in cxcywh space ----
        const float cost_bbox = fabsf(pb.x - tb.x) + fabsf(pb.y - tb.y)
                              + fabsf(pb.z - tb.z) + fabsf(pb.w - tb.w);

        // ---- GIoU in xyxy space ----
        const float bx0 = tb.x - 0.5f * tb.z, by0 = tb.y - 0.5f * tb.w;
        const float bx1 = tb.x + 0.5f * tb.z, by1 = tb.y + 0.5f * tb.w;
        const float area_b = (bx1 - bx0) * (by1 - by0);

        const float ltx = fmaxf(ax0, bx0), lty = fmaxf(ay0, by0);
        const float rbx = fminf(ax1, bx1), rby = fminf(ay1, by1);
        const float iw = fmaxf(rbx - ltx, 0.0f), ih = fmaxf(rby - lty, 0.0f);
        const float inter = iw * ih;
        const float uni = area_a + area_b - inter;
        const float iou = inter * __builtin_amdgcn_rcpf(uni);

        const float ex0 = fminf(ax0, bx0), ey0 = fminf(ay0, by0);
        const float ex1 = fmaxf(ax1, bx1), ey1 = fmaxf(ay1, by1);
        const float area_e = fmaxf(ex1 - ex0, 0.0f) * fmaxf(ey1 - ey0, 0.0f);
        const float giou = iou - (area_e - uni) * __builtin_amdgcn_rcpf(area_e);

        resp[j] = COST_BBOX * cost_bbox + COST_CLASS * cost_class
                + COST_GIOU * (-giou);
    }

    const int idx = blockIdx.x * 256 + tid;
    reinterpret_cast<float4*>(out)[idx] = res;
}

extern "C" void kernel_launch(void* const* d_in, const int* in_sizes, int n_in,
                              void* d_out, int out_size, void* d_ws, size_t ws_size,
                              hipStream_t stream) {
    const float* logits = (const float*)d_in[0];   // [16,1000,91] f32
    const float* pboxes = (const float*)d_in[1];   // [16,1000,4]  f32
    const int*   labels = (const int*)  d_in[2];   // [16,128]     i32
    const float* tboxes = (const float*)d_in[3];   // [16,128,4]   f32
    float* out = (float*)d_out;                    // [16,1000,128] f32

    const int total = BB * QQ * (TT / 4);          // 512,000 threads
    const int blocks = (total + 255) / 256;        // 2000
    matcher_kernel<<<blocks, 256, 0, stream>>>(logits, pboxes, labels, tboxes, out);
}